// Round 4
// baseline (326309.521 us; speedup 1.0000x reference)
//
#include <hip/hip_runtime.h>

// ============================================================================
// 2-layer LSTM, persistent kernel, MI355X — round 4.
// Round-3 root-cause: per-tick weight loads had LOOP-INVARIANT addresses ->
// LICM hoisted them -> ~130 weight regs demanded -> regalloc spilled ->
// per-tick spill fill+store = ~965 MB/phase scratch traffic thrashing L2 ->
// HBM-bound at 3.3 TB/s (495 GB writes / 195 GB reads per dispatch).
// Fixes:
//   * Empty asm "+v" on weight base offsets each phase -> loads cannot be
//     hoisted/CSEd across iterations; steady weight regs = 48 (W1 dbuf 32,
//     W0 JIT 16, X0 JIT). Arch VGPR demand ~105 << 128.
//   * Weights repacked by wconv into per-(u0,s,kway) fragment-contiguous
//     order: each ldW is one coalesced 4KB wave read at base+imm offset;
//     slice is L2-resident (3.1 MB unique/XCD).
//   * Everything else identical to round 3 (correct: absmax 4.9e-3): nt h
//     loads, sc01 h stores, relaxed+sc01 grid barrier, fused L0/L1 ticks.
// ============================================================================

typedef unsigned int u32;
typedef unsigned short u16;
typedef __attribute__((ext_vector_type(8))) short bf16x8;
typedef __attribute__((ext_vector_type(4))) float f32x4;

#define MFMA __builtin_amdgcn_mfma_f32_16x16x32_bf16
#define HB (256 * 1024)   // h buffer elems per parity

__device__ __forceinline__ u16 f2bf(float f) {
  u32 u = __float_as_uint(f);
  u += 0x7fffu + ((u >> 16) & 1u);   // RNE (inputs finite)
  return (u16)(u >> 16);
}
__device__ __forceinline__ float sigm(float v) { return 1.f / (1.f + __expf(-v)); }
__device__ __forceinline__ float tanh_(float v) { return 1.f - 2.f / (__expf(2.f * v) + 1.f); }

// ---- write-only / self-contained asm helpers (no liveness hazards) ----
__device__ __forceinline__ u32 ld_u32_sc01(const u32* p) {
  u32 v;
  asm volatile("global_load_dword %0, %1, off sc0 sc1\n\ts_waitcnt vmcnt(0)"
               : "=v"(v) : "v"(p) : "memory");
  return v;
}
__device__ __forceinline__ void st_u32_sc01(u32* p, u32 v) {
  asm volatile("global_store_dword %0, %1, off sc0 sc1" :: "v"(p), "v"(v) : "memory");
}
__device__ __forceinline__ void st_u16_sc01(u16* p, u32 v) {
  asm volatile("global_store_short %0, %1, off sc0 sc1" :: "v"(p), "v"(v) : "memory");
}
__device__ __forceinline__ void st_f32_sc01(float* p, float v) {
  asm volatile("global_store_dword %0, %1, off sc0 sc1" :: "v"(p), "v"(v) : "memory");
}

// ---------------- prologue: f32 -> bf16 packed-fragment weights ----------------
// Fragment identity shared with the main kernel (keep formulas in sync):
//   gate_row(f,i15,u0idx,s) = (2f + (i15>>3))*1024 + u0idx*16 + s*8 + (i15&7)
//   k(kway,c,jj,kq)         = (kway + 4*(2c+jj))*32 + kq*8   (+e, e=0..7)
__global__ void __launch_bounds__(256) wconv(
    const float* __restrict__ Wx0, const float* __restrict__ Wh0,
    const float* __restrict__ Wx1, const float* __restrict__ Wh1,
    u16* __restrict__ W1p, u16* __restrict__ W0p, u16* __restrict__ X0p) {
  const u32 NG1 = 1048576u;   // W1p bf16x8 groups (4096*2048/8)
  const u32 NG0 = 524288u;    // W0p groups        (4096*1024/8)
  const u32 NGX = 32768u;     // X0p groups        (4096*64/8)
  u32 g = blockIdx.x * 256u + threadIdx.x;
  const float* src; u16* dst;
  if (g < NG1) {
    u32 lane = g & 63u, f = (g >> 6) & 1u, jj = (g >> 7) & 1u, c = (g >> 8) & 7u;
    u32 kway = (g >> 11) & 3u, s = (g >> 13) & 1u, u0idx = g >> 14;
    u32 i15 = lane & 15u, kq = lane >> 4;
    u32 row = (2u * f + (i15 >> 3)) * 1024u + u0idx * 16u + s * 8u + (i15 & 7u);
    u32 k = (kway + 4u * (2u * c + jj)) * 32u + kq * 8u;
    src = (k < 1024u) ? Wx1 + (size_t)row * 1024 + k
                      : Wh1 + (size_t)row * 1024 + (k - 1024u);
    dst = W1p + (size_t)g * 8;
  } else if (g < NG1 + NG0) {
    u32 h = g - NG1;
    u32 lane = h & 63u, f = (h >> 6) & 1u, jj = (h >> 7) & 1u, c = (h >> 8) & 3u;
    u32 kway = (h >> 10) & 3u, s = (h >> 12) & 1u, u0idx = h >> 13;
    u32 i15 = lane & 15u, kq = lane >> 4;
    u32 row = (2u * f + (i15 >> 3)) * 1024u + u0idx * 16u + s * 8u + (i15 & 7u);
    u32 k = (kway + 4u * (2u * c + jj)) * 32u + kq * 8u;
    src = Wh0 + (size_t)row * 1024 + k;
    dst = W0p + (size_t)h * 8;
  } else if (g < NG1 + NG0 + NGX) {
    u32 h = g - NG1 - NG0;
    u32 lane = h & 63u, f = (h >> 6) & 1u, kway = (h >> 7) & 1u;
    u32 s = (h >> 8) & 1u, u0idx = h >> 9;
    u32 i15 = lane & 15u, kq = lane >> 4;
    u32 row = (2u * f + (i15 >> 3)) * 1024u + u0idx * 16u + s * 8u + (i15 & 7u);
    u32 k = kway * 32u + kq * 8u;
    src = Wx0 + (size_t)row * 64 + k;
    dst = X0p + (size_t)h * 8;
  } else return;
  float4 v0 = *(const float4*)src, v1 = *(const float4*)(src + 4);
  bf16x8 r;
  r[0] = (short)f2bf(v0.x); r[1] = (short)f2bf(v0.y);
  r[2] = (short)f2bf(v0.z); r[3] = (short)f2bf(v0.w);
  r[4] = (short)f2bf(v1.x); r[5] = (short)f2bf(v1.y);
  r[6] = (short)f2bf(v1.z); r[7] = (short)f2bf(v1.w);
  *(bf16x8*)dst = r;
}

// ---- MFMA tick macros (literal rb/bank so all reg indices are static) ----
#define H0T(rb, bank) do {                                                     \
  _Pragma("unroll")                                                            \
  for (int jj = 0; jj < 2; ++jj) {                                             \
    const int kin_ = (kway + (jj << 2)) << 5;                                  \
    _Pragma("unroll")                                                          \
    for (int mf = 0; mf < 4; ++mf) {                                           \
      bf16x8 a_ = readA(rb, mf, kin_);                                         \
      if (dL0) {                                                               \
        acc0[mf][0] = MFMA(a_, W0[jj][0], acc0[mf][0], 0, 0, 0);               \
        acc0[mf][1] = MFMA(a_, W0[jj][1], acc0[mf][1], 0, 0, 0);               \
      }                                                                        \
      if (dL1) {                                                               \
        acc1[mf][0] = MFMA(a_, W1[bank][jj][0], acc1[mf][0], 0, 0, 0);         \
        acc1[mf][1] = MFMA(a_, W1[bank][jj][1], acc1[mf][1], 0, 0, 0);         \
      }                                                                        \
    }                                                                          \
  }                                                                            \
} while (0)

#define H1T(rb, bank) do {                                                     \
  _Pragma("unroll")                                                            \
  for (int jj = 0; jj < 2; ++jj) {                                             \
    const int kin_ = (kway + (jj << 2)) << 5;                                  \
    _Pragma("unroll")                                                          \
    for (int mf = 0; mf < 4; ++mf) {                                           \
      bf16x8 a_ = readA(rb, mf, kin_);                                         \
      acc1[mf][0] = MFMA(a_, W1[bank][jj][0], acc1[mf][0], 0, 0, 0);           \
      acc1[mf][1] = MFMA(a_, W1[bank][jj][1], acc1[mf][1], 0, 0, 0);           \
    }                                                                          \
  }                                                                            \
} while (0)

__global__ void __launch_bounds__(512, 2)
lstm_persist(const float* __restrict__ x,
             const float* __restrict__ b0, const float* __restrict__ b1,
             const float* __restrict__ fcW, const float* __restrict__ fcb,
             const u16* __restrict__ W1p, const u16* __restrict__ W0p,
             const u16* __restrict__ X0p,
             u16* __restrict__ h0b, u16* __restrict__ h1b,
             float* __restrict__ h1f, u32* __restrict__ bar,
             float* __restrict__ out)
{
  const int tid = threadIdx.x, blk = blockIdx.x;
  const int lane = tid & 63, w = tid >> 6;
  const int s = w >> 2;        // n32 slice 0/1
  const int kway = w & 3;      // k-interleave lane
  const int m0 = (blk >> 6) << 6;   // batch tile base
  const int u0idx = blk & 63;
  const int u0 = u0idx << 4;        // hidden-unit base

  __shared__ short Abuf[2][64 * 256];   // 2 x 32KB A chunks
  __shared__ float gA[64][68];          // k-reduce region A
  __shared__ float gB[64][68];          // k-reduce region B
  __shared__ float cbuf[2][64][16];     // persistent c state

  for (int i = tid; i < 2 * 64 * 16; i += 512) ((float*)cbuf)[i] = 0.f;

  const int i15 = lane & 15, kq = lane >> 4;

  // packed-weight base offsets (u32 elem offsets; opaqued per phase vs LICM)
  u32 base1 = (u32)((((u0idx << 1) | s) << 2) | kway) * 16384u + (u32)lane * 8u;
  u32 base0 = (u32)((((u0idx << 1) | s) << 2) | kway) * 8192u  + (u32)lane * 8u;
  u32 baseX = (u32)((((u0idx << 1) | s) << 1) | kway) * 1024u  + (u32)lane * 8u;

  float bias0[2], bias1[2];
#pragma unroll
  for (int f = 0; f < 2; ++f) {
    int rowf = ((f << 1) + (i15 >> 3)) * 1024 + u0 + s * 8 + (i15 & 7);
    bias0[f] = (kway == 0) ? b0[rowf] : 0.f;   // bias only in one k-partial
    bias1[f] = (kway == 0) ? b1[rowf] : 0.f;
  }

  // staging address precompute
  int grow[4], ldsoff[4];
#pragma unroll
  for (int cc = 0; cc < 4; ++cc) {
    int call = (w << 2) | cc;
    int row = (call << 1) | (lane >> 5);
    int c = lane & 31;
    grow[cc]   = ((m0 + row) << 10) + (c << 3);
    ldsoff[cc] = (row << 8) + ((c ^ (row & 7)) << 3);
  }

  bf16x8 v[4];   // staging values — plain C++ (compiler-managed liveness)

  auto stage_ld = [&](const u16* src, int kbase) {
#pragma unroll
    for (int cc = 0; cc < 4; ++cc)
      v[cc] = __builtin_nontemporal_load((const bf16x8*)(src + grow[cc] + kbase));
  };
  auto stage_st = [&](int bsel) {
#pragma unroll
    for (int cc = 0; cc < 4; ++cc)
      *(bf16x8*)&Abuf[bsel][ldsoff[cc]] = v[cc];
  };

  auto stage_x = [&](int t) {   // x tile 64x64 f32 -> bf16 into Abuf[0]
    int row = tid >> 3, c = tid & 7;
    const float* g = x + ((size_t)(m0 + row) * 512 + t) * 64 + (c << 3);
    float4 v0 = *(const float4*)g;
    float4 v1 = *(const float4*)(g + 4);
    bf16x8 r;
    r[0] = (short)f2bf(v0.x); r[1] = (short)f2bf(v0.y);
    r[2] = (short)f2bf(v0.z); r[3] = (short)f2bf(v0.w);
    r[4] = (short)f2bf(v1.x); r[5] = (short)f2bf(v1.y);
    r[6] = (short)f2bf(v1.z); r[7] = (short)f2bf(v1.w);
    *(bf16x8*)&Abuf[0][(row << 8) + ((c ^ (row & 7)) << 3)] = r;
  };

  auto readA = [&](int bsel, int mf, int kin) -> bf16x8 {
    int row = (mf << 4) | i15;
    int c = ((kin >> 3) + kq) ^ (row & 7);
    return *(const bf16x8*)&Abuf[bsel][(row << 8) + (c << 3)];
  };

  bf16x8 W0[2][2], W1[2][2][2];   // W0 JIT single-bank; W1 [bank][jj][f] dbuf
  auto ldW0p = [&](int c) {       // W0 for chunk c (used same tick)
#pragma unroll
    for (int jj = 0; jj < 2; ++jj)
#pragma unroll
      for (int f = 0; f < 2; ++f)
        W0[jj][f] = *(const bf16x8*)(W0p + base0 + (u32)(c * 2048 + jj * 1024 + f * 512));
  };
  auto ldW1p = [&](int bank, int c) {   // W1 for chunk c -> bank (next tick)
#pragma unroll
    for (int jj = 0; jj < 2; ++jj)
#pragma unroll
      for (int f = 0; f < 2; ++f)
        W1[bank][jj][f] = *(const bf16x8*)(W1p + base1 + (u32)(c * 2048 + jj * 1024 + f * 512));
  };

  f32x4 acc0[4][2], acc1[4][2];
  auto acc_init = [&](f32x4 (&acc)[4][2], const float* bias) {
#pragma unroll
    for (int mf = 0; mf < 4; ++mf)
#pragma unroll
      for (int f = 0; f < 2; ++f) {
        acc[mf][f][0] = bias[f]; acc[mf][f][1] = bias[f];
        acc[mf][f][2] = bias[f]; acc[mf][f][3] = bias[f];
      }
  };

  auto reduce2 = [&](f32x4 (&acc)[4][2]) {
    if (kway < 2) {
      float (*g)[68] = kway ? gB : gA;
#pragma unroll
      for (int mf = 0; mf < 4; ++mf)
#pragma unroll
        for (int f = 0; f < 2; ++f)
#pragma unroll
          for (int r = 0; r < 4; ++r)
            g[(mf << 4) + (kq << 2) + r][(s << 5) + (f << 4) + i15] = acc[mf][f][r];
    }
    __syncthreads();
    if (kway >= 2) {
      float (*g)[68] = (kway == 3) ? gB : gA;
#pragma unroll
      for (int mf = 0; mf < 4; ++mf)
#pragma unroll
        for (int f = 0; f < 2; ++f)
#pragma unroll
          for (int r = 0; r < 4; ++r)
            g[(mf << 4) + (kq << 2) + r][(s << 5) + (f << 4) + i15] += acc[mf][f][r];
    }
    __syncthreads();
  };

  auto ew = [&](int L, u16* hdst, bool wf32) {
#pragma unroll
    for (int e0 = 0; e0 < 2; ++e0) {
      int e = tid + (e0 << 9);
      int row = e >> 4, un = e & 15;
      int cb = ((un >> 3) << 5) | (un & 7);
      float gi = gA[row][cb]      + gB[row][cb];
      float gf = gA[row][cb + 8]  + gB[row][cb + 8];
      float gg = gA[row][cb + 16] + gB[row][cb + 16];
      float go = gA[row][cb + 24] + gB[row][cb + 24];
      float ii = sigm(gi), ff = sigm(gf), g2 = tanh_(gg), oo = sigm(go);
      float c = ff * cbuf[L][row][un] + ii * g2;
      cbuf[L][row][un] = c;
      float h = oo * tanh_(c);
      size_t idx = ((size_t)(m0 + row) << 10) + u0 + un;
      st_u16_sc01(hdst + idx, (u32)f2bf(h));
      if (wf32) st_f32_sc01(h1f + idx, h);
    }
  };

  // ---------------- phase loop: phase t = { L0(t), L1(t-1) } ----------------
#pragma unroll 1
  for (int t = 0; t <= 512; ++t) {
    // opaque the weight offsets: kills LICM/CSE of the per-tick weight loads
    asm volatile("" : "+v"(base1), "+v"(base0), "+v"(baseX));

    const u16* h0rd = h0b + ((t + 1) & 1) * HB;
    u16* h0wr = h0b + (t & 1) * HB;
    const u16* h1rd = h1b + (t & 1) * HB;
    u16* h1wr = h1b + ((t + 1) & 1) * HB;
    const bool dL0 = (t < 512), dL1 = (t >= 1);

    if (dL0) acc_init(acc0, bias0);
    if (dL1) acc_init(acc1, bias1);

    if (dL0) stage_x(t);
    ldW1p(0, 0);
    stage_ld(h0rd, 0);
    __syncthreads();                    // x tile published
    if (dL0 && kway < 2) {              // x-tick: K=64 of layer0 (JIT X0)
      bf16x8 X0f0 = *(const bf16x8*)(X0p + baseX);
      bf16x8 X0f1 = *(const bf16x8*)(X0p + baseX + 512u);
      const int kin = kway << 5;
#pragma unroll
      for (int mf = 0; mf < 4; ++mf) {
        bf16x8 a = readA(0, mf, kin);
        acc0[mf][0] = MFMA(a, X0f0, acc0[mf][0], 0, 0, 0);
        acc0[mf][1] = MFMA(a, X0f1, acc0[mf][1], 0, 0, 0);
      }
    }
    stage_st(1);                        // h0 chunk0 -> buf1
    __syncthreads();

    // unified ticks: chunk c (h0 c<4, h1 c>=4), W1 bank alternates, W0 JIT
    stage_ld(h0rd, 256); ldW0p(0); ldW1p(1, 1); H0T(1, 0); stage_st(0); __syncthreads();
    stage_ld(h0rd, 512); ldW0p(1); ldW1p(0, 2); H0T(0, 1); stage_st(1); __syncthreads();
    stage_ld(h0rd, 768); ldW0p(2); ldW1p(1, 3); H0T(1, 0); stage_st(0); __syncthreads();
    if (dL1) stage_ld(h1rd, 0);
    ldW0p(3); ldW1p(0, 4); H0T(0, 1);
    if (dL1) stage_st(1);
    __syncthreads();
    if (dL1) {
      stage_ld(h1rd, 256); ldW1p(1, 5); H1T(1, 0); stage_st(0); __syncthreads();
      stage_ld(h1rd, 512); ldW1p(0, 6); H1T(0, 1); stage_st(1); __syncthreads();
      stage_ld(h1rd, 768); ldW1p(1, 7); H1T(1, 0); stage_st(0); __syncthreads();
      H1T(0, 1); __syncthreads();
    }

    if (dL0) { reduce2(acc0); ew(0, h0wr, false); }
    if (dL1) { __syncthreads(); reduce2(acc1); ew(1, h1wr, t == 512); }

    // ---- grid barrier: relaxed agent atomics + sc01 spins (proven live) ----
    __syncthreads();                    // drains vmcnt -> h stores at LLC
    if (tid == 0) {
      const int g = blk & 7;
      u32* gc   = bar + g * 32;
      u32* root = bar + 256;
      u32* gen  = bar + 288 + g * 32;
      const u32 p1 = (u32)(t + 1);
      __hip_atomic_fetch_add(gc, 1u, __ATOMIC_RELAXED, __HIP_MEMORY_SCOPE_AGENT);
      if (blk < 8) {
        while (ld_u32_sc01(gc) < 32u * p1) __builtin_amdgcn_s_sleep(4);
        __hip_atomic_fetch_add(root, 1u, __ATOMIC_RELAXED, __HIP_MEMORY_SCOPE_AGENT);
        while (ld_u32_sc01(root) < 8u * p1) __builtin_amdgcn_s_sleep(2);
        st_u32_sc01(gen, p1);
      } else {
        while (ld_u32_sc01(gen) < p1) __builtin_amdgcn_s_sleep(4);
      }
    }
    __syncthreads();
  }

  // ---------------- fc epilogue ----------------
  if (blk < 32) {
    const int row = (blk << 3) | w;
    const float* hrow = h1f + ((size_t)row << 10);
#pragma unroll 1
    for (int o = 0; o < 12; ++o) {
      const float* wrow = fcW + o * 1024;
      float p = 0.f;
#pragma unroll
      for (int j = 0; j < 16; ++j) {
        int k = (j << 6) | lane;
        p += __builtin_nontemporal_load(hrow + k) * wrow[k];
      }
#pragma unroll
      for (int off = 32; off > 0; off >>= 1) p += __shfl_down(p, off, 64);
      if (lane == 0) out[row * 12 + o] = p + fcb[o];
    }
  }
}

extern "C" void kernel_launch(void* const* d_in, const int* in_sizes, int n_in,
                              void* d_out, int out_size, void* d_ws, size_t ws_size,
                              hipStream_t stream) {
  (void)in_sizes; (void)n_in; (void)out_size; (void)ws_size;
  const float* x   = (const float*)d_in[0];
  const float* Wx0 = (const float*)d_in[1];
  const float* Wh0 = (const float*)d_in[2];
  const float* b0  = (const float*)d_in[3];
  const float* Wx1 = (const float*)d_in[4];
  const float* Wh1 = (const float*)d_in[5];
  const float* b1  = (const float*)d_in[6];
  const float* fcW = (const float*)d_in[7];
  const float* fcb = (const float*)d_in[8];

  char* ws = (char*)d_ws;
  u16* W1p   = (u16*)ws;                          // 16 MiB packed Wx1|Wh1
  u16* W0p   = (u16*)(ws + (16u << 20));          //  8 MiB packed Wh0
  u16* X0p   = (u16*)(ws + (24u << 20));          // 512 KiB packed Wx0
  u16* h0b   = (u16*)(ws + (25u << 20));          // 2 x 512 KiB
  u16* h1b   = (u16*)(ws + (26u << 20));          // 2 x 512 KiB
  float* h1f = (float*)(ws + (27u << 20));        // 1 MiB
  u32* bar   = (u32*)(ws + (28u << 20));          // counters

  hipMemsetAsync(ws + (25u << 20) + (1 << 19), 0, 1 << 19, stream);  // h0b[1]
  hipMemsetAsync(ws + (26u << 20) + (1 << 19), 0, 1 << 19, stream);  // h1b[1]
  hipMemsetAsync(bar, 0, 4096, stream);

  wconv<<<6272, 256, 0, stream>>>(Wx0, Wh0, Wx1, Wh1, W1p, W0p, X0p);
  lstm_persist<<<256, 512, 0, stream>>>(x, b0, b1, fcW, fcb,
                                        W1p, W0p, X0p,
                                        h0b, h1b, h1f, bar, (float*)d_out);
}

// Round 5
// 311551.758 us; speedup vs baseline: 1.0474x; 1.0474x over previous
//
#include <hip/hip_runtime.h>

// ============================================================================
// 2-layer LSTM, persistent kernel, MI355X — round 5.
// Root-cause chain (R1/R3/R4): weight arrays are readonly (__restrict const)
// -> IR-level LICM/GVN hoists ALL per-tick weight loads to the phase top
// (barriers don't clobber readonly memory) -> ~190 live weight VGPRs + 128
// acc AGPRs -> per-tick spill store+reload -> scratch thrashes L2 -> TB-scale
// HBM traffic (R4: 2.28 GB/phase writes), MfmaUtil < 1%.
// Fix: per-CALL opaque offset (asm volatile "+v" on the derived offset) for
// EVERY weight load group. Volatile asms are mutually ordered and cannot be
// CSE'd/hoisted; each load data-depends on its own asm -> loads stay in
// their tick, weight live range = one tick (<=48 VGPR). Steady pressure
// ~110 arch + 128 acc = 238 <= 256 budget -> no spill.
// Everything else identical to R4 (correct twice, absmax 4.9e-3).
// ============================================================================

typedef unsigned int u32;
typedef unsigned short u16;
typedef __attribute__((ext_vector_type(8))) short bf16x8;
typedef __attribute__((ext_vector_type(4))) float f32x4;

#define MFMA __builtin_amdgcn_mfma_f32_16x16x32_bf16
#define HB (256 * 1024)   // h buffer elems per parity

__device__ __forceinline__ u16 f2bf(float f) {
  u32 u = __float_as_uint(f);
  u += 0x7fffu + ((u >> 16) & 1u);   // RNE (inputs finite)
  return (u16)(u >> 16);
}
__device__ __forceinline__ float sigm(float v) { return 1.f / (1.f + __expf(-v)); }
__device__ __forceinline__ float tanh_(float v) { return 1.f - 2.f / (__expf(2.f * v) + 1.f); }

// ---- write-only / self-contained asm helpers (no liveness hazards) ----
__device__ __forceinline__ u32 ld_u32_sc01(const u32* p) {
  u32 v;
  asm volatile("global_load_dword %0, %1, off sc0 sc1\n\ts_waitcnt vmcnt(0)"
               : "=v"(v) : "v"(p) : "memory");
  return v;
}
__device__ __forceinline__ void st_u32_sc01(u32* p, u32 v) {
  asm volatile("global_store_dword %0, %1, off sc0 sc1" :: "v"(p), "v"(v) : "memory");
}
__device__ __forceinline__ void st_u16_sc01(u16* p, u32 v) {
  asm volatile("global_store_short %0, %1, off sc0 sc1" :: "v"(p), "v"(v) : "memory");
}
__device__ __forceinline__ void st_f32_sc01(float* p, float v) {
  asm volatile("global_store_dword %0, %1, off sc0 sc1" :: "v"(p), "v"(v) : "memory");
}

// ---------------- prologue: f32 -> bf16 packed-fragment weights ----------------
// Fragment identity shared with the main kernel (keep formulas in sync):
//   gate_row(f,i15,u0idx,s) = (2f + (i15>>3))*1024 + u0idx*16 + s*8 + (i15&7)
//   k(kway,c,jj,kq)         = (kway + 4*(2c+jj))*32 + kq*8   (+e, e=0..7)
__global__ void __launch_bounds__(256) wconv(
    const float* __restrict__ Wx0, const float* __restrict__ Wh0,
    const float* __restrict__ Wx1, const float* __restrict__ Wh1,
    u16* __restrict__ W1p, u16* __restrict__ W0p, u16* __restrict__ X0p) {
  const u32 NG1 = 1048576u;   // W1p bf16x8 groups (4096*2048/8)
  const u32 NG0 = 524288u;    // W0p groups        (4096*1024/8)
  const u32 NGX = 32768u;     // X0p groups        (4096*64/8)
  u32 g = blockIdx.x * 256u + threadIdx.x;
  const float* src; u16* dst;
  if (g < NG1) {
    u32 lane = g & 63u, f = (g >> 6) & 1u, jj = (g >> 7) & 1u, c = (g >> 8) & 7u;
    u32 kway = (g >> 11) & 3u, s = (g >> 13) & 1u, u0idx = g >> 14;
    u32 i15 = lane & 15u, kq = lane >> 4;
    u32 row = (2u * f + (i15 >> 3)) * 1024u + u0idx * 16u + s * 8u + (i15 & 7u);
    u32 k = (kway + 4u * (2u * c + jj)) * 32u + kq * 8u;
    src = (k < 1024u) ? Wx1 + (size_t)row * 1024 + k
                      : Wh1 + (size_t)row * 1024 + (k - 1024u);
    dst = W1p + (size_t)g * 8;
  } else if (g < NG1 + NG0) {
    u32 h = g - NG1;
    u32 lane = h & 63u, f = (h >> 6) & 1u, jj = (h >> 7) & 1u, c = (h >> 8) & 3u;
    u32 kway = (h >> 10) & 3u, s = (h >> 12) & 1u, u0idx = h >> 13;
    u32 i15 = lane & 15u, kq = lane >> 4;
    u32 row = (2u * f + (i15 >> 3)) * 1024u + u0idx * 16u + s * 8u + (i15 & 7u);
    u32 k = (kway + 4u * (2u * c + jj)) * 32u + kq * 8u;
    src = Wh0 + (size_t)row * 1024 + k;
    dst = W0p + (size_t)h * 8;
  } else if (g < NG1 + NG0 + NGX) {
    u32 h = g - NG1 - NG0;
    u32 lane = h & 63u, f = (h >> 6) & 1u, kway = (h >> 7) & 1u;
    u32 s = (h >> 8) & 1u, u0idx = h >> 9;
    u32 i15 = lane & 15u, kq = lane >> 4;
    u32 row = (2u * f + (i15 >> 3)) * 1024u + u0idx * 16u + s * 8u + (i15 & 7u);
    u32 k = kway * 32u + kq * 8u;
    src = Wx0 + (size_t)row * 64 + k;
    dst = X0p + (size_t)h * 8;
  } else return;
  float4 v0 = *(const float4*)src, v1 = *(const float4*)(src + 4);
  bf16x8 r;
  r[0] = (short)f2bf(v0.x); r[1] = (short)f2bf(v0.y);
  r[2] = (short)f2bf(v0.z); r[3] = (short)f2bf(v0.w);
  r[4] = (short)f2bf(v1.x); r[5] = (short)f2bf(v1.y);
  r[6] = (short)f2bf(v1.z); r[7] = (short)f2bf(v1.w);
  *(bf16x8*)dst = r;
}

// ---- MFMA tick macros (literal rb/bank so all reg indices are static) ----
#define H0T(rb, bank) do {                                                     \
  _Pragma("unroll")                                                            \
  for (int jj = 0; jj < 2; ++jj) {                                             \
    const int kin_ = (kway + (jj << 2)) << 5;                                  \
    _Pragma("unroll")                                                          \
    for (int mf = 0; mf < 4; ++mf) {                                           \
      bf16x8 a_ = readA(rb, mf, kin_);                                         \
      if (dL0) {                                                               \
        acc0[mf][0] = MFMA(a_, W0[jj][0], acc0[mf][0], 0, 0, 0);               \
        acc0[mf][1] = MFMA(a_, W0[jj][1], acc0[mf][1], 0, 0, 0);               \
      }                                                                        \
      if (dL1) {                                                               \
        acc1[mf][0] = MFMA(a_, W1[bank][jj][0], acc1[mf][0], 0, 0, 0);         \
        acc1[mf][1] = MFMA(a_, W1[bank][jj][1], acc1[mf][1], 0, 0, 0);         \
      }                                                                        \
    }                                                                          \
  }                                                                            \
} while (0)

#define H1T(rb, bank) do {                                                     \
  _Pragma("unroll")                                                            \
  for (int jj = 0; jj < 2; ++jj) {                                             \
    const int kin_ = (kway + (jj << 2)) << 5;                                  \
    _Pragma("unroll")                                                          \
    for (int mf = 0; mf < 4; ++mf) {                                           \
      bf16x8 a_ = readA(rb, mf, kin_);                                         \
      acc1[mf][0] = MFMA(a_, W1[bank][jj][0], acc1[mf][0], 0, 0, 0);           \
      acc1[mf][1] = MFMA(a_, W1[bank][jj][1], acc1[mf][1], 0, 0, 0);           \
    }                                                                          \
  }                                                                            \
} while (0)

__global__ void __launch_bounds__(512, 2)
lstm_persist(const float* __restrict__ x,
             const float* __restrict__ b0, const float* __restrict__ b1,
             const float* __restrict__ fcW, const float* __restrict__ fcb,
             const u16* __restrict__ W1p, const u16* __restrict__ W0p,
             const u16* __restrict__ X0p,
             u16* __restrict__ h0b, u16* __restrict__ h1b,
             float* __restrict__ h1f, u32* __restrict__ bar,
             float* __restrict__ out)
{
  const int tid = threadIdx.x, blk = blockIdx.x;
  const int lane = tid & 63, w = tid >> 6;
  const int s = w >> 2;        // n32 slice 0/1
  const int kway = w & 3;      // k-interleave lane
  const int m0 = (blk >> 6) << 6;   // batch tile base
  const int u0idx = blk & 63;
  const int u0 = u0idx << 4;        // hidden-unit base

  __shared__ short Abuf[2][64 * 256];   // 2 x 32KB A chunks
  __shared__ float gA[64][68];          // k-reduce region A
  __shared__ float gB[64][68];          // k-reduce region B
  __shared__ float cbuf[2][64][16];     // persistent c state

  for (int i = tid; i < 2 * 64 * 16; i += 512) ((float*)cbuf)[i] = 0.f;

  const int i15 = lane & 15, kq = lane >> 4;

  // packed-weight base offsets (u32 elem offsets)
  const u32 base1 = (u32)((((u0idx << 1) | s) << 2) | kway) * 16384u + (u32)lane * 8u;
  const u32 base0 = (u32)((((u0idx << 1) | s) << 2) | kway) * 8192u  + (u32)lane * 8u;
  const u32 baseX = (u32)((((u0idx << 1) | s) << 1) | kway) * 1024u  + (u32)lane * 8u;

  float bias0[2], bias1[2];
#pragma unroll
  for (int f = 0; f < 2; ++f) {
    int rowf = ((f << 1) + (i15 >> 3)) * 1024 + u0 + s * 8 + (i15 & 7);
    bias0[f] = (kway == 0) ? b0[rowf] : 0.f;   // bias only in one k-partial
    bias1[f] = (kway == 0) ? b1[rowf] : 0.f;
  }

  // staging address precompute
  int grow[4], ldsoff[4];
#pragma unroll
  for (int cc = 0; cc < 4; ++cc) {
    int call = (w << 2) | cc;
    int row = (call << 1) | (lane >> 5);
    int c = lane & 31;
    grow[cc]   = ((m0 + row) << 10) + (c << 3);
    ldsoff[cc] = (row << 8) + ((c ^ (row & 7)) << 3);
  }

  bf16x8 v[4];   // staging values — plain C++ (compiler-managed liveness)

  auto stage_ld = [&](const u16* src, int kbase) {
#pragma unroll
    for (int cc = 0; cc < 4; ++cc)
      v[cc] = __builtin_nontemporal_load((const bf16x8*)(src + grow[cc] + kbase));
  };
  auto stage_st = [&](int bsel) {
#pragma unroll
    for (int cc = 0; cc < 4; ++cc)
      *(bf16x8*)&Abuf[bsel][ldsoff[cc]] = v[cc];
  };

  auto stage_x = [&](int t) {   // x tile 64x64 f32 -> bf16 into Abuf[0]
    int row = tid >> 3, c = tid & 7;
    const float* g = x + ((size_t)(m0 + row) * 512 + t) * 64 + (c << 3);
    float4 v0 = *(const float4*)g;
    float4 v1 = *(const float4*)(g + 4);
    bf16x8 r;
    r[0] = (short)f2bf(v0.x); r[1] = (short)f2bf(v0.y);
    r[2] = (short)f2bf(v0.z); r[3] = (short)f2bf(v0.w);
    r[4] = (short)f2bf(v1.x); r[5] = (short)f2bf(v1.y);
    r[6] = (short)f2bf(v1.z); r[7] = (short)f2bf(v1.w);
    *(bf16x8*)&Abuf[0][(row << 8) + ((c ^ (row & 7)) << 3)] = r;
  };

  auto readA = [&](int bsel, int mf, int kin) -> bf16x8 {
    int row = (mf << 4) | i15;
    int c = ((kin >> 3) + kq) ^ (row & 7);
    return *(const bf16x8*)&Abuf[bsel][(row << 8) + (c << 3)];
  };

  bf16x8 W0[2][2], W1[2][2][2];   // W0 JIT single-bank; W1 [bank][jj][f] dbuf
  // Per-CALL opaque offset: volatile asm is ordered/unhoistable/un-CSE-able;
  // every load data-depends on it -> loads stay in their tick (the fix).
  auto ldW0p = [&](int c) {       // W0 for chunk c (used same tick)
    u32 b = base0 + (u32)(c * 2048);
    asm volatile("" : "+v"(b));
#pragma unroll
    for (int jj = 0; jj < 2; ++jj)
#pragma unroll
      for (int f = 0; f < 2; ++f)
        W0[jj][f] = *(const bf16x8*)(W0p + b + (u32)(jj * 1024 + f * 512));
  };
  auto ldW1p = [&](int bank, int c) {   // W1 for chunk c -> bank (next tick)
    u32 b = base1 + (u32)(c * 2048);
    asm volatile("" : "+v"(b));
#pragma unroll
    for (int jj = 0; jj < 2; ++jj)
#pragma unroll
      for (int f = 0; f < 2; ++f)
        W1[bank][jj][f] = *(const bf16x8*)(W1p + b + (u32)(jj * 1024 + f * 512));
  };

  f32x4 acc0[4][2], acc1[4][2];
  auto acc_init = [&](f32x4 (&acc)[4][2], const float* bias) {
#pragma unroll
    for (int mf = 0; mf < 4; ++mf)
#pragma unroll
      for (int f = 0; f < 2; ++f) {
        acc[mf][f][0] = bias[f]; acc[mf][f][1] = bias[f];
        acc[mf][f][2] = bias[f]; acc[mf][f][3] = bias[f];
      }
  };

  auto reduce2 = [&](f32x4 (&acc)[4][2]) {
    if (kway < 2) {
      float (*g)[68] = kway ? gB : gA;
#pragma unroll
      for (int mf = 0; mf < 4; ++mf)
#pragma unroll
        for (int f = 0; f < 2; ++f)
#pragma unroll
          for (int r = 0; r < 4; ++r)
            g[(mf << 4) + (kq << 2) + r][(s << 5) + (f << 4) + i15] = acc[mf][f][r];
    }
    __syncthreads();
    if (kway >= 2) {
      float (*g)[68] = (kway == 3) ? gB : gA;
#pragma unroll
      for (int mf = 0; mf < 4; ++mf)
#pragma unroll
        for (int f = 0; f < 2; ++f)
#pragma unroll
          for (int r = 0; r < 4; ++r)
            g[(mf << 4) + (kq << 2) + r][(s << 5) + (f << 4) + i15] += acc[mf][f][r];
    }
    __syncthreads();
  };

  auto ew = [&](int L, u16* hdst, bool wf32) {
#pragma unroll
    for (int e0 = 0; e0 < 2; ++e0) {
      int e = tid + (e0 << 9);
      int row = e >> 4, un = e & 15;
      int cb = ((un >> 3) << 5) | (un & 7);
      float gi = gA[row][cb]      + gB[row][cb];
      float gf = gA[row][cb + 8]  + gB[row][cb + 8];
      float gg = gA[row][cb + 16] + gB[row][cb + 16];
      float go = gA[row][cb + 24] + gB[row][cb + 24];
      float ii = sigm(gi), ff = sigm(gf), g2 = tanh_(gg), oo = sigm(go);
      float c = ff * cbuf[L][row][un] + ii * g2;
      cbuf[L][row][un] = c;
      float h = oo * tanh_(c);
      size_t idx = ((size_t)(m0 + row) << 10) + u0 + un;
      st_u16_sc01(hdst + idx, (u32)f2bf(h));
      if (wf32) st_f32_sc01(h1f + idx, h);
    }
  };

  // ---------------- phase loop: phase t = { L0(t), L1(t-1) } ----------------
#pragma unroll 1
  for (int t = 0; t <= 512; ++t) {
    const u16* h0rd = h0b + ((t + 1) & 1) * HB;
    u16* h0wr = h0b + (t & 1) * HB;
    const u16* h1rd = h1b + (t & 1) * HB;
    u16* h1wr = h1b + ((t + 1) & 1) * HB;
    const bool dL0 = (t < 512), dL1 = (t >= 1);

    if (dL0) acc_init(acc0, bias0);
    if (dL1) acc_init(acc1, bias1);

    if (dL0) stage_x(t);
    ldW1p(0, 0);
    stage_ld(h0rd, 0);
    __syncthreads();                    // x tile published
    if (dL0 && kway < 2) {              // x-tick: K=64 of layer0 (JIT X0)
      u32 bx = baseX;
      asm volatile("" : "+v"(bx));
      bf16x8 X0f0 = *(const bf16x8*)(X0p + bx);
      bf16x8 X0f1 = *(const bf16x8*)(X0p + bx + 512u);
      const int kin = kway << 5;
#pragma unroll
      for (int mf = 0; mf < 4; ++mf) {
        bf16x8 a = readA(0, mf, kin);
        acc0[mf][0] = MFMA(a, X0f0, acc0[mf][0], 0, 0, 0);
        acc0[mf][1] = MFMA(a, X0f1, acc0[mf][1], 0, 0, 0);
      }
    }
    stage_st(1);                        // h0 chunk0 -> buf1
    __syncthreads();

    // unified ticks: chunk c (h0 c<4, h1 c>=4), W1 bank alternates, W0 JIT
    stage_ld(h0rd, 256); ldW0p(0); ldW1p(1, 1); H0T(1, 0); stage_st(0); __syncthreads();
    stage_ld(h0rd, 512); ldW0p(1); ldW1p(0, 2); H0T(0, 1); stage_st(1); __syncthreads();
    stage_ld(h0rd, 768); ldW0p(2); ldW1p(1, 3); H0T(1, 0); stage_st(0); __syncthreads();
    if (dL1) stage_ld(h1rd, 0);
    ldW0p(3); ldW1p(0, 4); H0T(0, 1);
    if (dL1) stage_st(1);
    __syncthreads();
    if (dL1) {
      stage_ld(h1rd, 256); ldW1p(1, 5); H1T(1, 0); stage_st(0); __syncthreads();
      stage_ld(h1rd, 512); ldW1p(0, 6); H1T(0, 1); stage_st(1); __syncthreads();
      stage_ld(h1rd, 768); ldW1p(1, 7); H1T(1, 0); stage_st(0); __syncthreads();
      H1T(0, 1); __syncthreads();
    }

    if (dL0) { reduce2(acc0); ew(0, h0wr, false); }
    if (dL1) { __syncthreads(); reduce2(acc1); ew(1, h1wr, t == 512); }

    // ---- grid barrier: relaxed agent atomics + sc01 spins (proven live) ----
    __syncthreads();                    // drains vmcnt -> h stores at LLC
    if (tid == 0) {
      const int g = blk & 7;
      u32* gc   = bar + g * 32;
      u32* root = bar + 256;
      u32* gen  = bar + 288 + g * 32;
      const u32 p1 = (u32)(t + 1);
      __hip_atomic_fetch_add(gc, 1u, __ATOMIC_RELAXED, __HIP_MEMORY_SCOPE_AGENT);
      if (blk < 8) {
        while (ld_u32_sc01(gc) < 32u * p1) __builtin_amdgcn_s_sleep(4);
        __hip_atomic_fetch_add(root, 1u, __ATOMIC_RELAXED, __HIP_MEMORY_SCOPE_AGENT);
        while (ld_u32_sc01(root) < 8u * p1) __builtin_amdgcn_s_sleep(2);
        st_u32_sc01(gen, p1);
      } else {
        while (ld_u32_sc01(gen) < p1) __builtin_amdgcn_s_sleep(4);
      }
    }
    __syncthreads();
  }

  // ---------------- fc epilogue ----------------
  if (blk < 32) {
    const int row = (blk << 3) | w;
    const float* hrow = h1f + ((size_t)row << 10);
#pragma unroll 1
    for (int o = 0; o < 12; ++o) {
      const float* wrow = fcW + o * 1024;
      float p = 0.f;
#pragma unroll
      for (int j = 0; j < 16; ++j) {
        int k = (j << 6) | lane;
        p += __builtin_nontemporal_load(hrow + k) * wrow[k];
      }
#pragma unroll
      for (int off = 32; off > 0; off >>= 1) p += __shfl_down(p, off, 64);
      if (lane == 0) out[row * 12 + o] = p + fcb[o];
    }
  }
}

extern "C" void kernel_launch(void* const* d_in, const int* in_sizes, int n_in,
                              void* d_out, int out_size, void* d_ws, size_t ws_size,
                              hipStream_t stream) {
  (void)in_sizes; (void)n_in; (void)out_size; (void)ws_size;
  const float* x   = (const float*)d_in[0];
  const float* Wx0 = (const float*)d_in[1];
  const float* Wh0 = (const float*)d_in[2];
  const float* b0  = (const float*)d_in[3];
  const float* Wx1 = (const float*)d_in[4];
  const float* Wh1 = (const float*)d_in[5];
  const float* b1  = (const float*)d_in[6];
  const float* fcW = (const float*)d_in[7];
  const float* fcb = (const float*)d_in[8];

  char* ws = (char*)d_ws;
  u16* W1p   = (u16*)ws;                          // 16 MiB packed Wx1|Wh1
  u16* W0p   = (u16*)(ws + (16u << 20));          //  8 MiB packed Wh0
  u16* X0p   = (u16*)(ws + (24u << 20));          // 512 KiB packed Wx0
  u16* h0b   = (u16*)(ws + (25u << 20));          // 2 x 512 KiB
  u16* h1b   = (u16*)(ws + (26u << 20));          // 2 x 512 KiB
  float* h1f = (float*)(ws + (27u << 20));        // 1 MiB
  u32* bar   = (u32*)(ws + (28u << 20));          // counters

  hipMemsetAsync(ws + (25u << 20) + (1 << 19), 0, 1 << 19, stream);  // h0b[1]
  hipMemsetAsync(ws + (26u << 20) + (1 << 19), 0, 1 << 19, stream);  // h1b[1]
  hipMemsetAsync(bar, 0, 4096, stream);

  wconv<<<6272, 256, 0, stream>>>(Wx0, Wh0, Wx1, Wh1, W1p, W0p, X0p);
  lstm_persist<<<256, 512, 0, stream>>>(x, b0, b1, fcW, fcb,
                                        W1p, W0p, X0p,
                                        h0b, h1b, h1f, bar, (float*)d_out);
}

// Round 6
// 234102.246 us; speedup vs baseline: 1.3939x; 1.3308x over previous
//
#include <hip/hip_runtime.h>

// ============================================================================
// 2-layer LSTM, persistent kernel, MI355X — round 6.
// R1-R5 root-cause (revised): __launch_bounds__(512, 2) caps the allocator at
// 128 VGPRs/thread. Body demand (staging 16 + W 32-64 + addr ~24 + acc 64 in
// the unified VGPR/AGPR file) > 128 -> per-tick spill store+reload in the
// phase loop -> 2.28 GB/phase scratch traffic (= the whole 1.17 TB WRITE_SIZE)
// -> HBM/L2 thrash, MfmaUtil 0.4%. VGPR_Count==128 every round was the tell.
// LDS (106 KB) already limits to 1 WG/CU = 2 waves/EU, so ",2" bought nothing.
// Fixes:
//   * __launch_bounds__(512, 1): VGPR cap 512. Expect ~160-200 alloc, 0 spill.
//   * Lower concurrent demand: W single-bank JIT per tick (<=32 W regs live),
//     h stores packed as u32 (halves sc01 store count).
//   * Everything else byte-identical to R5 (correct 3x, absmax 4.9e-3):
//     packed weights, nt h loads, sc01 h stores, relaxed+sc01 grid barrier.
// ============================================================================

typedef unsigned int u32;
typedef unsigned short u16;
typedef __attribute__((ext_vector_type(8))) short bf16x8;
typedef __attribute__((ext_vector_type(4))) float f32x4;

#define MFMA __builtin_amdgcn_mfma_f32_16x16x32_bf16
#define HB (256 * 1024)   // h buffer elems per parity

__device__ __forceinline__ u16 f2bf(float f) {
  u32 u = __float_as_uint(f);
  u += 0x7fffu + ((u >> 16) & 1u);   // RNE (inputs finite)
  return (u16)(u >> 16);
}
__device__ __forceinline__ float sigm(float v) { return 1.f / (1.f + __expf(-v)); }
__device__ __forceinline__ float tanh_(float v) { return 1.f - 2.f / (__expf(2.f * v) + 1.f); }

// ---- write-only / self-contained asm helpers (no liveness hazards) ----
__device__ __forceinline__ u32 ld_u32_sc01(const u32* p) {
  u32 v;
  asm volatile("global_load_dword %0, %1, off sc0 sc1\n\ts_waitcnt vmcnt(0)"
               : "=v"(v) : "v"(p) : "memory");
  return v;
}
__device__ __forceinline__ void st_u32_sc01(u32* p, u32 v) {
  asm volatile("global_store_dword %0, %1, off sc0 sc1" :: "v"(p), "v"(v) : "memory");
}
__device__ __forceinline__ void st_f32_sc01(float* p, float v) {
  asm volatile("global_store_dword %0, %1, off sc0 sc1" :: "v"(p), "v"(v) : "memory");
}

// ---------------- prologue: f32 -> bf16 packed-fragment weights ----------------
//   gate_row(f,i15,u0idx,s) = (2f + (i15>>3))*1024 + u0idx*16 + s*8 + (i15&7)
//   k(kway,c,jj,kq)         = (kway + 4*(2c+jj))*32 + kq*8   (+e, e=0..7)
__global__ void __launch_bounds__(256) wconv(
    const float* __restrict__ Wx0, const float* __restrict__ Wh0,
    const float* __restrict__ Wx1, const float* __restrict__ Wh1,
    u16* __restrict__ W1p, u16* __restrict__ W0p, u16* __restrict__ X0p) {
  const u32 NG1 = 1048576u;   // W1p bf16x8 groups (4096*2048/8)
  const u32 NG0 = 524288u;    // W0p groups        (4096*1024/8)
  const u32 NGX = 32768u;     // X0p groups        (4096*64/8)
  u32 g = blockIdx.x * 256u + threadIdx.x;
  const float* src; u16* dst;
  if (g < NG1) {
    u32 lane = g & 63u, f = (g >> 6) & 1u, jj = (g >> 7) & 1u, c = (g >> 8) & 7u;
    u32 kway = (g >> 11) & 3u, s = (g >> 13) & 1u, u0idx = g >> 14;
    u32 i15 = lane & 15u, kq = lane >> 4;
    u32 row = (2u * f + (i15 >> 3)) * 1024u + u0idx * 16u + s * 8u + (i15 & 7u);
    u32 k = (kway + 4u * (2u * c + jj)) * 32u + kq * 8u;
    src = (k < 1024u) ? Wx1 + (size_t)row * 1024 + k
                      : Wh1 + (size_t)row * 1024 + (k - 1024u);
    dst = W1p + (size_t)g * 8;
  } else if (g < NG1 + NG0) {
    u32 h = g - NG1;
    u32 lane = h & 63u, f = (h >> 6) & 1u, jj = (h >> 7) & 1u, c = (h >> 8) & 3u;
    u32 kway = (h >> 10) & 3u, s = (h >> 12) & 1u, u0idx = h >> 13;
    u32 i15 = lane & 15u, kq = lane >> 4;
    u32 row = (2u * f + (i15 >> 3)) * 1024u + u0idx * 16u + s * 8u + (i15 & 7u);
    u32 k = (kway + 4u * (2u * c + jj)) * 32u + kq * 8u;
    src = Wh0 + (size_t)row * 1024 + k;
    dst = W0p + (size_t)h * 8;
  } else if (g < NG1 + NG0 + NGX) {
    u32 h = g - NG1 - NG0;
    u32 lane = h & 63u, f = (h >> 6) & 1u, kway = (h >> 7) & 1u;
    u32 s = (h >> 8) & 1u, u0idx = h >> 9;
    u32 i15 = lane & 15u, kq = lane >> 4;
    u32 row = (2u * f + (i15 >> 3)) * 1024u + u0idx * 16u + s * 8u + (i15 & 7u);
    u32 k = kway * 32u + kq * 8u;
    src = Wx0 + (size_t)row * 64 + k;
    dst = X0p + (size_t)h * 8;
  } else return;
  float4 v0 = *(const float4*)src, v1 = *(const float4*)(src + 4);
  bf16x8 r;
  r[0] = (short)f2bf(v0.x); r[1] = (short)f2bf(v0.y);
  r[2] = (short)f2bf(v0.z); r[3] = (short)f2bf(v0.w);
  r[4] = (short)f2bf(v1.x); r[5] = (short)f2bf(v1.y);
  r[6] = (short)f2bf(v1.z); r[7] = (short)f2bf(v1.w);
  *(bf16x8*)dst = r;
}

// ---- MFMA tick macros (single-bank W; literal rb so reg indices static) ----
#define H0T(rb) do {                                                           \
  _Pragma("unroll")                                                            \
  for (int jj = 0; jj < 2; ++jj) {                                             \
    const int kin_ = (kway + (jj << 2)) << 5;                                  \
    _Pragma("unroll")                                                          \
    for (int mf = 0; mf < 4; ++mf) {                                           \
      bf16x8 a_ = readA(rb, mf, kin_);                                         \
      if (dL0) {                                                               \
        acc0[mf][0] = MFMA(a_, W0[jj][0], acc0[mf][0], 0, 0, 0);               \
        acc0[mf][1] = MFMA(a_, W0[jj][1], acc0[mf][1], 0, 0, 0);               \
      }                                                                        \
      if (dL1) {                                                               \
        acc1[mf][0] = MFMA(a_, W1[jj][0], acc1[mf][0], 0, 0, 0);               \
        acc1[mf][1] = MFMA(a_, W1[jj][1], acc1[mf][1], 0, 0, 0);               \
      }                                                                        \
    }                                                                          \
  }                                                                            \
} while (0)

#define H1T(rb) do {                                                           \
  _Pragma("unroll")                                                            \
  for (int jj = 0; jj < 2; ++jj) {                                             \
    const int kin_ = (kway + (jj << 2)) << 5;                                  \
    _Pragma("unroll")                                                          \
    for (int mf = 0; mf < 4; ++mf) {                                           \
      bf16x8 a_ = readA(rb, mf, kin_);                                         \
      acc1[mf][0] = MFMA(a_, W1[jj][0], acc1[mf][0], 0, 0, 0);                 \
      acc1[mf][1] = MFMA(a_, W1[jj][1], acc1[mf][1], 0, 0, 0);                 \
    }                                                                          \
  }                                                                            \
} while (0)

__global__ void __launch_bounds__(512, 1)
lstm_persist(const float* __restrict__ x,
             const float* __restrict__ b0, const float* __restrict__ b1,
             const float* __restrict__ fcW, const float* __restrict__ fcb,
             const u16* __restrict__ W1p, const u16* __restrict__ W0p,
             const u16* __restrict__ X0p,
             u16* __restrict__ h0b, u16* __restrict__ h1b,
             float* __restrict__ h1f, u32* __restrict__ bar,
             float* __restrict__ out)
{
  const int tid = threadIdx.x, blk = blockIdx.x;
  const int lane = tid & 63, w = tid >> 6;
  const int s = w >> 2;        // n32 slice 0/1
  const int kway = w & 3;      // k-interleave lane
  const int m0 = (blk >> 6) << 6;   // batch tile base
  const int u0idx = blk & 63;
  const int u0 = u0idx << 4;        // hidden-unit base

  __shared__ short Abuf[2][64 * 256];   // 2 x 32KB A chunks
  __shared__ float gA[64][68];          // k-reduce region A
  __shared__ float gB[64][68];          // k-reduce region B
  __shared__ float cbuf[2][64][16];     // persistent c state

  for (int i = tid; i < 2 * 64 * 16; i += 512) ((float*)cbuf)[i] = 0.f;

  const int i15 = lane & 15, kq = lane >> 4;

  // packed-weight base offsets (u32 elem offsets)
  const u32 base1 = (u32)((((u0idx << 1) | s) << 2) | kway) * 16384u + (u32)lane * 8u;
  const u32 base0 = (u32)((((u0idx << 1) | s) << 2) | kway) * 8192u  + (u32)lane * 8u;
  const u32 baseX = (u32)((((u0idx << 1) | s) << 1) | kway) * 1024u  + (u32)lane * 8u;

  float bias0[2], bias1[2];
#pragma unroll
  for (int f = 0; f < 2; ++f) {
    int rowf = ((f << 1) + (i15 >> 3)) * 1024 + u0 + s * 8 + (i15 & 7);
    bias0[f] = (kway == 0) ? b0[rowf] : 0.f;   // bias only in one k-partial
    bias1[f] = (kway == 0) ? b1[rowf] : 0.f;
  }

  // staging address precompute
  int grow[4], ldsoff[4];
#pragma unroll
  for (int cc = 0; cc < 4; ++cc) {
    int call = (w << 2) | cc;
    int row = (call << 1) | (lane >> 5);
    int c = lane & 31;
    grow[cc]   = ((m0 + row) << 10) + (c << 3);
    ldsoff[cc] = (row << 8) + ((c ^ (row & 7)) << 3);
  }

  bf16x8 v[4];   // staging values (compiler-managed liveness)

  auto stage_ld = [&](const u16* src, int kbase) {
#pragma unroll
    for (int cc = 0; cc < 4; ++cc)
      v[cc] = __builtin_nontemporal_load((const bf16x8*)(src + grow[cc] + kbase));
  };
  auto stage_st = [&](int bsel) {
#pragma unroll
    for (int cc = 0; cc < 4; ++cc)
      *(bf16x8*)&Abuf[bsel][ldsoff[cc]] = v[cc];
  };

  auto stage_x = [&](int t) {   // x tile 64x64 f32 -> bf16 into Abuf[0]
    int row = tid >> 3, c = tid & 7;
    const float* g = x + ((size_t)(m0 + row) * 512 + t) * 64 + (c << 3);
    float4 v0 = *(const float4*)g;
    float4 v1 = *(const float4*)(g + 4);
    bf16x8 r;
    r[0] = (short)f2bf(v0.x); r[1] = (short)f2bf(v0.y);
    r[2] = (short)f2bf(v0.z); r[3] = (short)f2bf(v0.w);
    r[4] = (short)f2bf(v1.x); r[5] = (short)f2bf(v1.y);
    r[6] = (short)f2bf(v1.z); r[7] = (short)f2bf(v1.w);
    *(bf16x8*)&Abuf[0][(row << 8) + ((c ^ (row & 7)) << 3)] = r;
  };

  auto readA = [&](int bsel, int mf, int kin) -> bf16x8 {
    int row = (mf << 4) | i15;
    int c = ((kin >> 3) + kq) ^ (row & 7);
    return *(const bf16x8*)&Abuf[bsel][(row << 8) + (c << 3)];
  };

  bf16x8 W0[2][2], W1[2][2];   // single-bank JIT weights [jj][f]
  // Per-call opaque offset pins each chunk's loads inside its tick.
  auto ldW0p = [&](int c) {
    u32 b = base0 + (u32)(c * 2048);
    asm volatile("" : "+v"(b));
#pragma unroll
    for (int jj = 0; jj < 2; ++jj)
#pragma unroll
      for (int f = 0; f < 2; ++f)
        W0[jj][f] = *(const bf16x8*)(W0p + b + (u32)(jj * 1024 + f * 512));
  };
  auto ldW1p = [&](int c) {
    u32 b = base1 + (u32)(c * 2048);
    asm volatile("" : "+v"(b));
#pragma unroll
    for (int jj = 0; jj < 2; ++jj)
#pragma unroll
      for (int f = 0; f < 2; ++f)
        W1[jj][f] = *(const bf16x8*)(W1p + b + (u32)(jj * 1024 + f * 512));
  };

  f32x4 acc0[4][2], acc1[4][2];
  auto acc_init = [&](f32x4 (&acc)[4][2], const float* bias) {
#pragma unroll
    for (int mf = 0; mf < 4; ++mf)
#pragma unroll
      for (int f = 0; f < 2; ++f) {
        acc[mf][f][0] = bias[f]; acc[mf][f][1] = bias[f];
        acc[mf][f][2] = bias[f]; acc[mf][f][3] = bias[f];
      }
  };

  auto reduce2 = [&](f32x4 (&acc)[4][2]) {
    if (kway < 2) {
      float (*g)[68] = kway ? gB : gA;
#pragma unroll
      for (int mf = 0; mf < 4; ++mf)
#pragma unroll
        for (int f = 0; f < 2; ++f)
#pragma unroll
          for (int r = 0; r < 4; ++r)
            g[(mf << 4) + (kq << 2) + r][(s << 5) + (f << 4) + i15] = acc[mf][f][r];
    }
    __syncthreads();
    if (kway >= 2) {
      float (*g)[68] = (kway == 3) ? gB : gA;
#pragma unroll
      for (int mf = 0; mf < 4; ++mf)
#pragma unroll
        for (int f = 0; f < 2; ++f)
#pragma unroll
          for (int r = 0; r < 4; ++r)
            g[(mf << 4) + (kq << 2) + r][(s << 5) + (f << 4) + i15] += acc[mf][f][r];
    }
    __syncthreads();
  };

  auto ew = [&](int L, u16* hdst, bool wf32) {
    // thread -> (row, un..un+1): 64 rows x 16 units, 2 adjacent units/thread
    int row = tid >> 3, un = (tid & 7) << 1;
    float h2[2];
#pragma unroll
    for (int q = 0; q < 2; ++q) {
      int u = un + q;
      int cb = ((u >> 3) << 5) | (u & 7);
      float gi = gA[row][cb]      + gB[row][cb];
      float gf = gA[row][cb + 8]  + gB[row][cb + 8];
      float gg = gA[row][cb + 16] + gB[row][cb + 16];
      float go = gA[row][cb + 24] + gB[row][cb + 24];
      float ii = sigm(gi), ff = sigm(gf), g2 = tanh_(gg), oo = sigm(go);
      float c = ff * cbuf[L][row][u] + ii * g2;
      cbuf[L][row][u] = c;
      h2[q] = oo * tanh_(c);
    }
    size_t idx = ((size_t)(m0 + row) << 10) + u0 + un;
    u32 pk = (u32)f2bf(h2[0]) | ((u32)f2bf(h2[1]) << 16);
    st_u32_sc01((u32*)(hdst + idx), pk);
    if (wf32) { st_f32_sc01(h1f + idx, h2[0]); st_f32_sc01(h1f + idx + 1, h2[1]); }
  };

  // ---------------- phase loop: phase t = { L0(t), L1(t-1) } ----------------
#pragma unroll 1
  for (int t = 0; t <= 512; ++t) {
    const u16* h0rd = h0b + ((t + 1) & 1) * HB;
    u16* h0wr = h0b + (t & 1) * HB;
    const u16* h1rd = h1b + (t & 1) * HB;
    u16* h1wr = h1b + ((t + 1) & 1) * HB;
    const bool dL0 = (t < 512), dL1 = (t >= 1);

    if (dL0) acc_init(acc0, bias0);
    if (dL1) acc_init(acc1, bias1);

    if (dL0) stage_x(t);
    stage_ld(h0rd, 0);
    __syncthreads();                    // x tile published
    if (dL0 && kway < 2) {              // x-tick: K=64 of layer0 (JIT X0)
      u32 bx = baseX;
      asm volatile("" : "+v"(bx));
      bf16x8 X0f0 = *(const bf16x8*)(X0p + bx);
      bf16x8 X0f1 = *(const bf16x8*)(X0p + bx + 512u);
      const int kin = kway << 5;
#pragma unroll
      for (int mf = 0; mf < 4; ++mf) {
        bf16x8 a = readA(0, mf, kin);
        acc0[mf][0] = MFMA(a, X0f0, acc0[mf][0], 0, 0, 0);
        acc0[mf][1] = MFMA(a, X0f1, acc0[mf][1], 0, 0, 0);
      }
    }
    stage_st(1);                        // h0 chunk0 -> buf1
    __syncthreads();

    // fused ticks 1-4: h0 chunk (c-1) feeds L0 (W0) and L1 (Wx1 part of W1)
    stage_ld(h0rd, 256); ldW0p(0); ldW1p(0); H0T(1); stage_st(0); __syncthreads();
    stage_ld(h0rd, 512); ldW0p(1); ldW1p(1); H0T(0); stage_st(1); __syncthreads();
    stage_ld(h0rd, 768); ldW0p(2); ldW1p(2); H0T(1); stage_st(0); __syncthreads();
    if (dL1) stage_ld(h1rd, 0);
    ldW0p(3); ldW1p(3); H0T(0);
    if (dL1) stage_st(1);
    __syncthreads();
    // L1-only ticks 5-8: h1 chunks, W1 chunks 4-7
    if (dL1) {
      stage_ld(h1rd, 256); ldW1p(4); H1T(1); stage_st(0); __syncthreads();
      stage_ld(h1rd, 512); ldW1p(5); H1T(0); stage_st(1); __syncthreads();
      stage_ld(h1rd, 768); ldW1p(6); H1T(1); stage_st(0); __syncthreads();
      ldW1p(7); H1T(0); __syncthreads();
    }

    if (dL0) { reduce2(acc0); ew(0, h0wr, false); }
    if (dL1) { __syncthreads(); reduce2(acc1); ew(1, h1wr, t == 512); }

    // ---- grid barrier: relaxed agent atomics + sc01 spins (proven live) ----
    __syncthreads();                    // drains vmcnt -> h stores at LLC
    if (tid == 0) {
      const int g = blk & 7;
      u32* gc   = bar + g * 32;
      u32* root = bar + 256;
      u32* gen  = bar + 288 + g * 32;
      const u32 p1 = (u32)(t + 1);
      __hip_atomic_fetch_add(gc, 1u, __ATOMIC_RELAXED, __HIP_MEMORY_SCOPE_AGENT);
      if (blk < 8) {
        while (ld_u32_sc01(gc) < 32u * p1) __builtin_amdgcn_s_sleep(4);
        __hip_atomic_fetch_add(root, 1u, __ATOMIC_RELAXED, __HIP_MEMORY_SCOPE_AGENT);
        while (ld_u32_sc01(root) < 8u * p1) __builtin_amdgcn_s_sleep(2);
        st_u32_sc01(gen, p1);
      } else {
        while (ld_u32_sc01(gen) < p1) __builtin_amdgcn_s_sleep(4);
      }
    }
    __syncthreads();
  }

  // ---------------- fc epilogue ----------------
  if (blk < 32) {
    const int row = (blk << 3) | w;
    const float* hrow = h1f + ((size_t)row << 10);
#pragma unroll 1
    for (int o = 0; o < 12; ++o) {
      const float* wrow = fcW + o * 1024;
      float p = 0.f;
#pragma unroll
      for (int j = 0; j < 16; ++j) {
        int k = (j << 6) | lane;
        p += __builtin_nontemporal_load(hrow + k) * wrow[k];
      }
#pragma unroll
      for (int off = 32; off > 0; off >>= 1) p += __shfl_down(p, off, 64);
      if (lane == 0) out[row * 12 + o] = p + fcb[o];
    }
  }
}

extern "C" void kernel_launch(void* const* d_in, const int* in_sizes, int n_in,
                              void* d_out, int out_size, void* d_ws, size_t ws_size,
                              hipStream_t stream) {
  (void)in_sizes; (void)n_in; (void)out_size; (void)ws_size;
  const float* x   = (const float*)d_in[0];
  const float* Wx0 = (const float*)d_in[1];
  const float* Wh0 = (const float*)d_in[2];
  const float* b0  = (const float*)d_in[3];
  const float* Wx1 = (const float*)d_in[4];
  const float* Wh1 = (const float*)d_in[5];
  const float* b1  = (const float*)d_in[6];
  const float* fcW = (const float*)d_in[7];
  const float* fcb = (const float*)d_in[8];

  char* ws = (char*)d_ws;
  u16* W1p   = (u16*)ws;                          // 16 MiB packed Wx1|Wh1
  u16* W0p   = (u16*)(ws + (16u << 20));          //  8 MiB packed Wh0
  u16* X0p   = (u16*)(ws + (24u << 20));          // 512 KiB packed Wx0
  u16* h0b   = (u16*)(ws + (25u << 20));          // 2 x 512 KiB
  u16* h1b   = (u16*)(ws + (26u << 20));          // 2 x 512 KiB
  float* h1f = (float*)(ws + (27u << 20));        // 1 MiB
  u32* bar   = (u32*)(ws + (28u << 20));          // counters

  hipMemsetAsync(ws + (25u << 20) + (1 << 19), 0, 1 << 19, stream);  // h0b[1]
  hipMemsetAsync(ws + (26u << 20) + (1 << 19), 0, 1 << 19, stream);  // h1b[1]
  hipMemsetAsync(bar, 0, 4096, stream);

  wconv<<<6272, 256, 0, stream>>>(Wx0, Wh0, Wx1, Wh1, W1p, W0p, X0p);
  lstm_persist<<<256, 512, 0, stream>>>(x, b0, b1, fcW, fcb,
                                        W1p, W0p, X0p,
                                        h0b, h1b, h1f, bar, (float*)d_out);
}

// Round 7
// 8451.316 us; speedup vs baseline: 38.6105x; 27.7001x over previous
//
#include <hip/hip_runtime.h>

// ============================================================================
// 2-layer LSTM, persistent kernel, MI355X — round 7 (register-first redesign).
// R1-R6 disease: 512-thr WG = 2 waves/SIMD = 256-reg hard cap, compiler splits
// 128 arch + 128 acc (VGPR_Count pinned at 128 all 6 rounds). Arch demand of
// the fused dual-layer body > 128 -> per-tick spill fill+store -> GB/phase
// scratch traffic (R6: 755 GB WRITE), MfmaUtil < 1%.
// Redesign: 512 WGs x 256 thr (4 waves), 2 WGs/CU, ONE layer per WG
// (blk<256: L0(t); blk>=256: L1(t-1)). Single acc (64), dbuf W (64),
// staging v[8] (32) -> ~200 regs < 256 cap. Proven pieces kept verbatim:
// packed weights + fragment formulas, sc01 h stores, nt h loads,
// relaxed+sc01 grid barrier, reduce2/ew math (absmax 4.9e-3 four times).
// ============================================================================

typedef unsigned int u32;
typedef unsigned short u16;
typedef __attribute__((ext_vector_type(8))) short bf16x8;
typedef __attribute__((ext_vector_type(4))) float f32x4;

#define MFMA __builtin_amdgcn_mfma_f32_16x16x32_bf16
#define HB (256 * 1024)   // h buffer elems per parity

__device__ __forceinline__ u16 f2bf(float f) {
  u32 u = __float_as_uint(f);
  u += 0x7fffu + ((u >> 16) & 1u);   // RNE (inputs finite)
  return (u16)(u >> 16);
}
__device__ __forceinline__ float sigm(float v) { return 1.f / (1.f + __expf(-v)); }
__device__ __forceinline__ float tanh_(float v) { return 1.f - 2.f / (__expf(2.f * v) + 1.f); }

// ---- write-only / self-contained asm helpers ----
__device__ __forceinline__ u32 ld_u32_sc01(const u32* p) {
  u32 v;
  asm volatile("global_load_dword %0, %1, off sc0 sc1\n\ts_waitcnt vmcnt(0)"
               : "=v"(v) : "v"(p) : "memory");
  return v;
}
__device__ __forceinline__ void st_u32_sc01(u32* p, u32 v) {
  asm volatile("global_store_dword %0, %1, off sc0 sc1" :: "v"(p), "v"(v) : "memory");
}
__device__ __forceinline__ void st_f32_sc01(float* p, float v) {
  asm volatile("global_store_dword %0, %1, off sc0 sc1" :: "v"(p), "v"(v) : "memory");
}

// ---------------- prologue: f32 -> bf16 packed-fragment weights ----------------
// (unchanged from R4-R6; packing formulas shared with the main kernel)
__global__ void __launch_bounds__(256) wconv(
    const float* __restrict__ Wx0, const float* __restrict__ Wh0,
    const float* __restrict__ Wx1, const float* __restrict__ Wh1,
    u16* __restrict__ W1p, u16* __restrict__ W0p, u16* __restrict__ X0p) {
  const u32 NG1 = 1048576u, NG0 = 524288u, NGX = 32768u;
  u32 g = blockIdx.x * 256u + threadIdx.x;
  const float* src; u16* dst;
  if (g < NG1) {
    u32 lane = g & 63u, f = (g >> 6) & 1u, jj = (g >> 7) & 1u, c = (g >> 8) & 7u;
    u32 kway = (g >> 11) & 3u, s = (g >> 13) & 1u, u0idx = g >> 14;
    u32 i15 = lane & 15u, kq = lane >> 4;
    u32 row = (2u * f + (i15 >> 3)) * 1024u + u0idx * 16u + s * 8u + (i15 & 7u);
    u32 k = (kway + 4u * (2u * c + jj)) * 32u + kq * 8u;
    src = (k < 1024u) ? Wx1 + (size_t)row * 1024 + k
                      : Wh1 + (size_t)row * 1024 + (k - 1024u);
    dst = W1p + (size_t)g * 8;
  } else if (g < NG1 + NG0) {
    u32 h = g - NG1;
    u32 lane = h & 63u, f = (h >> 6) & 1u, jj = (h >> 7) & 1u, c = (h >> 8) & 3u;
    u32 kway = (h >> 10) & 3u, s = (h >> 12) & 1u, u0idx = h >> 13;
    u32 i15 = lane & 15u, kq = lane >> 4;
    u32 row = (2u * f + (i15 >> 3)) * 1024u + u0idx * 16u + s * 8u + (i15 & 7u);
    u32 k = (kway + 4u * (2u * c + jj)) * 32u + kq * 8u;
    src = Wh0 + (size_t)row * 1024 + k;
    dst = W0p + (size_t)h * 8;
  } else if (g < NG1 + NG0 + NGX) {
    u32 h = g - NG1 - NG0;
    u32 lane = h & 63u, f = (h >> 6) & 1u, kway = (h >> 7) & 1u;
    u32 s = (h >> 8) & 1u, u0idx = h >> 9;
    u32 i15 = lane & 15u, kq = lane >> 4;
    u32 row = (2u * f + (i15 >> 3)) * 1024u + u0idx * 16u + s * 8u + (i15 & 7u);
    u32 k = kway * 32u + kq * 8u;
    src = Wx0 + (size_t)row * 64 + k;
    dst = X0p + (size_t)h * 8;
  } else return;
  float4 v0 = *(const float4*)src, v1 = *(const float4*)(src + 4);
  bf16x8 r;
  r[0] = (short)f2bf(v0.x); r[1] = (short)f2bf(v0.y);
  r[2] = (short)f2bf(v0.z); r[3] = (short)f2bf(v0.w);
  r[4] = (short)f2bf(v1.x); r[5] = (short)f2bf(v1.y);
  r[6] = (short)f2bf(v1.z); r[7] = (short)f2bf(v1.w);
  *(bf16x8*)dst = r;
}

// ---- per-chunk weight load: bank literal, per-call opaque offset ----
#define LDW(bank, c) do {                                                      \
  u32 o0_ = bW[0] + (u32)((c) * 2048), o1_ = bW[1] + (u32)((c) * 2048);        \
  asm volatile("" : "+v"(o0_), "+v"(o1_));                                     \
  _Pragma("unroll")                                                            \
  for (int jj_ = 0; jj_ < 2; ++jj_)                                            \
    _Pragma("unroll")                                                          \
    for (int f_ = 0; f_ < 2; ++f_) {                                           \
      W[bank][jj_][0][f_] = *(const bf16x8*)(WP + o0_ + (u32)(jj_*1024+f_*512));\
      W[bank][jj_][1][f_] = *(const bf16x8*)(WP + o1_ + (u32)(jj_*1024+f_*512));\
    }                                                                          \
} while (0)

// ---- per-chunk MFMA: 2 ksteps x 4 m-frags x 4 (s,f) n-frags = 32 MFMA ----
#define CHUNK(bank) do {                                                       \
  _Pragma("unroll")                                                            \
  for (int jj_ = 0; jj_ < 2; ++jj_) {                                          \
    const int kin_ = (kway + (jj_ << 2)) << 5;                                 \
    _Pragma("unroll")                                                          \
    for (int mf_ = 0; mf_ < 4; ++mf_) {                                        \
      bf16x8 a_ = readA(mf_, kin_);                                            \
      _Pragma("unroll")                                                        \
      for (int s_ = 0; s_ < 2; ++s_)                                           \
        _Pragma("unroll")                                                      \
        for (int f_ = 0; f_ < 2; ++f_)                                         \
          acc[mf_][s_][f_] = MFMA(a_, W[bank][jj_][s_][f_],                    \
                                  acc[mf_][s_][f_], 0, 0, 0);                  \
    }                                                                          \
  }                                                                            \
} while (0)

__global__ void __launch_bounds__(256, 2)
lstm_persist(const float* __restrict__ x,
             const float* __restrict__ b0, const float* __restrict__ b1,
             const float* __restrict__ fcW, const float* __restrict__ fcb,
             const u16* __restrict__ W1p, const u16* __restrict__ W0p,
             const u16* __restrict__ X0p,
             u16* __restrict__ h0b, u16* __restrict__ h1b,
             float* __restrict__ h1f, u32* __restrict__ bar,
             float* __restrict__ out)
{
  const int tid = threadIdx.x, blk = blockIdx.x;
  const int lane = tid & 63, w = tid >> 6;
  const int kway = w;                 // wave = k-split lane (0..3)
  const int L = blk >> 8;             // 0: layer0 WG, 1: layer1 WG
  const int sub = blk & 255;
  const int m0 = (sub >> 6) << 6;     // batch tile base
  const int u0idx = sub & 63;
  const int u0 = u0idx << 4;          // hidden-unit base

  __shared__ short Abuf[64 * 256];    // single 32KB A chunk
  __shared__ float gA[64][68];        // k-reduce region A
  __shared__ float gB[64][68];        // k-reduce region B
  __shared__ float cbuf[64][16];      // persistent c state (own layer)

  for (int i = tid; i < 64 * 16; i += 256) ((float*)cbuf)[i] = 0.f;

  const int i15 = lane & 15, kq = lane >> 4;

  // packed-weight base offsets for both s-halves (u32 elem offsets)
  u32 bW[2], bX[2];
#pragma unroll
  for (int s_ = 0; s_ < 2; ++s_) {
    u32 key = (u32)((u0idx << 1) | s_);
    bW[s_] = ((key << 2) | (u32)kway) * (L ? 16384u : 8192u) + (u32)lane * 8u;
    bX[s_] = ((key << 1) | (u32)kway) * 1024u + (u32)lane * 8u;  // kway<2 only
  }
  const u16* WP = L ? W1p : W0p;

  float bias[2][2];
#pragma unroll
  for (int s_ = 0; s_ < 2; ++s_)
#pragma unroll
    for (int f_ = 0; f_ < 2; ++f_) {
      int rowf = ((f_ << 1) + (i15 >> 3)) * 1024 + u0 + s_ * 8 + (i15 & 7);
      bias[s_][f_] = (kway == 0) ? (L ? b1[rowf] : b0[rowf]) : 0.f;
    }

  // staging maps: 2048 bf16x8 slots (64 rows x 32), 8 per thread
  int grow[8], ldsoff[8];
#pragma unroll
  for (int cc = 0; cc < 8; ++cc) {
    int slot = cc * 256 + tid;
    int row = slot >> 5, c = slot & 31;
    grow[cc]   = ((m0 + row) << 10) + (c << 3);
    ldsoff[cc] = (row << 8) + ((c ^ (row & 7)) << 3);
  }

  bf16x8 v[8];
  auto stage_ld = [&](const u16* src, int kbase) {
#pragma unroll
    for (int cc = 0; cc < 8; ++cc)
      v[cc] = __builtin_nontemporal_load((const bf16x8*)(src + grow[cc] + kbase));
  };
  auto stage_st = [&]() {
#pragma unroll
    for (int cc = 0; cc < 8; ++cc)
      *(bf16x8*)&Abuf[ldsoff[cc]] = v[cc];
  };

  auto readA = [&](int mf, int kin) -> bf16x8 {
    int row = (mf << 4) | i15;
    int c = ((kin >> 3) + kq) ^ (row & 7);
    return *(const bf16x8*)&Abuf[(row << 8) + (c << 3)];
  };

  bf16x8 W[2][2][2][2];   // [bank][jj][s][f] double-banked weights (64 regs)
  f32x4 acc[4][2][2];     // [mf][s][f] (64 regs)

  auto acc_init = [&]() {
#pragma unroll
    for (int mf = 0; mf < 4; ++mf)
#pragma unroll
      for (int s_ = 0; s_ < 2; ++s_)
#pragma unroll
        for (int f_ = 0; f_ < 2; ++f_) {
          float bv = bias[s_][f_];
          acc[mf][s_][f_][0] = bv; acc[mf][s_][f_][1] = bv;
          acc[mf][s_][f_][2] = bv; acc[mf][s_][f_][3] = bv;
        }
  };

  auto reduce2 = [&]() {   // 4 kway partials -> gA + gB
    if (kway < 2) {
      float (*g)[68] = kway ? gB : gA;
#pragma unroll
      for (int mf = 0; mf < 4; ++mf)
#pragma unroll
        for (int s_ = 0; s_ < 2; ++s_)
#pragma unroll
          for (int f_ = 0; f_ < 2; ++f_)
#pragma unroll
            for (int r = 0; r < 4; ++r)
              g[(mf << 4) + (kq << 2) + r][(s_ << 5) + (f_ << 4) + i15] = acc[mf][s_][f_][r];
    }
    __syncthreads();
    if (kway >= 2) {
      float (*g)[68] = (kway == 3) ? gB : gA;
#pragma unroll
      for (int mf = 0; mf < 4; ++mf)
#pragma unroll
        for (int s_ = 0; s_ < 2; ++s_)
#pragma unroll
          for (int f_ = 0; f_ < 2; ++f_)
#pragma unroll
            for (int r = 0; r < 4; ++r)
              g[(mf << 4) + (kq << 2) + r][(s_ << 5) + (f_ << 4) + i15] += acc[mf][s_][f_][r];
    }
    __syncthreads();
  };

  auto ew = [&](u16* hdst, bool wf32) {
    int row = tid >> 2, un = (tid & 3) << 2;   // 4 units per thread
    float hq[4];
#pragma unroll
    for (int q = 0; q < 4; ++q) {
      int u = un + q;
      int cb = ((u >> 3) << 5) | (u & 7);
      float gi = gA[row][cb]      + gB[row][cb];
      float gf = gA[row][cb + 8]  + gB[row][cb + 8];
      float gg = gA[row][cb + 16] + gB[row][cb + 16];
      float go = gA[row][cb + 24] + gB[row][cb + 24];
      float ii = sigm(gi), ff = sigm(gf), g2 = tanh_(gg), oo = sigm(go);
      float c = ff * cbuf[row][u] + ii * g2;
      cbuf[row][u] = c;
      hq[q] = oo * tanh_(c);
    }
    size_t idx = ((size_t)(m0 + row) << 10) + u0 + un;
    st_u32_sc01((u32*)(hdst + idx),     (u32)f2bf(hq[0]) | ((u32)f2bf(hq[1]) << 16));
    st_u32_sc01((u32*)(hdst + idx + 2), (u32)f2bf(hq[2]) | ((u32)f2bf(hq[3]) << 16));
    if (wf32) {
      st_f32_sc01(h1f + idx,     hq[0]); st_f32_sc01(h1f + idx + 1, hq[1]);
      st_f32_sc01(h1f + idx + 2, hq[2]); st_f32_sc01(h1f + idx + 3, hq[3]);
    }
  };

  auto gridbar = [&](int t) {
    __syncthreads();                  // drains vmcnt -> sc01 h stores at LLC
    if (tid == 0) {
      const int g = blk & 7;
      u32* gc   = bar + g * 32;
      u32* root = bar + 256;
      u32* gen  = bar + 288 + g * 32;
      const u32 p1 = (u32)(t + 1);
      __hip_atomic_fetch_add(gc, 1u, __ATOMIC_RELAXED, __HIP_MEMORY_SCOPE_AGENT);
      if (blk < 8) {
        while (ld_u32_sc01(gc) < 64u * p1) __builtin_amdgcn_s_sleep(4);
        __hip_atomic_fetch_add(root, 1u, __ATOMIC_RELAXED, __HIP_MEMORY_SCOPE_AGENT);
        while (ld_u32_sc01(root) < 8u * p1) __builtin_amdgcn_s_sleep(2);
        st_u32_sc01(gen, p1);
      } else {
        while (ld_u32_sc01(gen) < p1) __builtin_amdgcn_s_sleep(4);
      }
    }
    __syncthreads();
  };

  if (L == 0) {
    // ---------------- layer-0 WGs: compute h0(t) each phase ----------------
    auto stage_x = [&](int t) {   // x tile 64x64 f32 -> bf16 into Abuf
      int row = tid >> 2, c4 = tid & 3;
      const float* g = x + ((size_t)(m0 + row) * 512 + t) * 64 + (c4 << 4);
      float4 a0 = *(const float4*)g,       a1 = *(const float4*)(g + 4);
      float4 a2 = *(const float4*)(g + 8), a3 = *(const float4*)(g + 12);
      bf16x8 r0, r1;
      r0[0] = (short)f2bf(a0.x); r0[1] = (short)f2bf(a0.y);
      r0[2] = (short)f2bf(a0.z); r0[3] = (short)f2bf(a0.w);
      r0[4] = (short)f2bf(a1.x); r0[5] = (short)f2bf(a1.y);
      r0[6] = (short)f2bf(a1.z); r0[7] = (short)f2bf(a1.w);
      r1[0] = (short)f2bf(a2.x); r1[1] = (short)f2bf(a2.y);
      r1[2] = (short)f2bf(a2.z); r1[3] = (short)f2bf(a2.w);
      r1[4] = (short)f2bf(a3.x); r1[5] = (short)f2bf(a3.y);
      r1[6] = (short)f2bf(a3.z); r1[7] = (short)f2bf(a3.w);
      int c = c4 << 1;
      *(bf16x8*)&Abuf[(row << 8) + (((c    ) ^ (row & 7)) << 3)] = r0;
      *(bf16x8*)&Abuf[(row << 8) + (((c + 1) ^ (row & 7)) << 3)] = r1;
    };

#pragma unroll 1
    for (int t = 0; t <= 512; ++t) {
      if (t < 512) {
        const u16* h0rd = h0b + ((t + 1) & 1) * HB;
        u16* h0wr = h0b + (t & 1) * HB;
        acc_init();
        stage_x(t);                        // Abuf <- x tile
        stage_ld(h0rd, 0);                 // prefetch h0 chunk0
        bf16x8 X[2][2];
        if (kway < 2) {
          u32 ox0 = bX[0], ox1 = bX[1];
          asm volatile("" : "+v"(ox0), "+v"(ox1));
          X[0][0] = *(const bf16x8*)(X0p + ox0);
          X[0][1] = *(const bf16x8*)(X0p + ox0 + 512u);
          X[1][0] = *(const bf16x8*)(X0p + ox1);
          X[1][1] = *(const bf16x8*)(X0p + ox1 + 512u);
        }
        LDW(0, 0);                         // W0 chunk0 -> bank0
        __syncthreads();                   // x tile ready
        if (kway < 2) {                    // x-tick (ksteps 0,1 of K=64)
          const int kin = kway << 5;
#pragma unroll
          for (int mf = 0; mf < 4; ++mf) {
            bf16x8 a = readA(mf, kin);
#pragma unroll
            for (int s_ = 0; s_ < 2; ++s_)
#pragma unroll
              for (int f_ = 0; f_ < 2; ++f_)
                acc[mf][s_][f_] = MFMA(a, X[s_][f_], acc[mf][s_][f_], 0, 0, 0);
          }
        }
        __syncthreads();                   // x consumed
        stage_st(); __syncthreads();       // Abuf <- h0 chunk0
        stage_ld(h0rd, 256); LDW(1, 1); CHUNK(0); __syncthreads();
        stage_st(); __syncthreads();
        stage_ld(h0rd, 512); LDW(0, 2); CHUNK(1); __syncthreads();
        stage_st(); __syncthreads();
        stage_ld(h0rd, 768); LDW(1, 3); CHUNK(0); __syncthreads();
        stage_st(); __syncthreads();
        CHUNK(1);
        reduce2();
        ew(h0wr, false);
      }
      gridbar(t);
    }
  } else {
    // -------------- layer-1 WGs: compute h1(t-1) each phase --------------
#pragma unroll 1
    for (int t = 0; t <= 512; ++t) {
      if (t >= 1) {
        const u16* h0rd = h0b + ((t + 1) & 1) * HB;   // h0(t-1)
        const u16* h1rd = h1b + (t & 1) * HB;         // h1(t-2)
        u16* h1wr = h1b + ((t + 1) & 1) * HB;         // h1(t-1)
        acc_init();
        stage_ld(h0rd, 0); LDW(0, 0);
        stage_st(); __syncthreads();
        stage_ld(h0rd, 256); LDW(1, 1); CHUNK(0); __syncthreads();
        stage_st(); __syncthreads();
        stage_ld(h0rd, 512); LDW(0, 2); CHUNK(1); __syncthreads();
        stage_st(); __syncthreads();
        stage_ld(h0rd, 768); LDW(1, 3); CHUNK(0); __syncthreads();
        stage_st(); __syncthreads();
        stage_ld(h1rd, 0);   LDW(0, 4); CHUNK(1); __syncthreads();
        stage_st(); __syncthreads();
        stage_ld(h1rd, 256); LDW(1, 5); CHUNK(0); __syncthreads();
        stage_st(); __syncthreads();
        stage_ld(h1rd, 512); LDW(0, 6); CHUNK(1); __syncthreads();
        stage_st(); __syncthreads();
        stage_ld(h1rd, 768); LDW(1, 7); CHUNK(0); __syncthreads();
        stage_st(); __syncthreads();
        CHUNK(1);
        reduce2();
        ew(h1wr, t == 512);
      }
      gridbar(t);
    }
  }

  // ---------------- fc epilogue: out = h1(511) @ fcW.T + fcb ----------------
  if (blk < 64) {
    const int row = (blk << 2) | w;
    const float* hrow = h1f + ((size_t)row << 10);
#pragma unroll 1
    for (int o = 0; o < 12; ++o) {
      const float* wrow = fcW + o * 1024;
      float p = 0.f;
#pragma unroll
      for (int j = 0; j < 16; ++j) {
        int k = (j << 6) | lane;
        p += __builtin_nontemporal_load(hrow + k) * wrow[k];
      }
#pragma unroll
      for (int off = 32; off > 0; off >>= 1) p += __shfl_down(p, off, 64);
      if (lane == 0) out[row * 12 + o] = p + fcb[o];
    }
  }
}

extern "C" void kernel_launch(void* const* d_in, const int* in_sizes, int n_in,
                              void* d_out, int out_size, void* d_ws, size_t ws_size,
                              hipStream_t stream) {
  (void)in_sizes; (void)n_in; (void)out_size; (void)ws_size;
  const float* x   = (const float*)d_in[0];
  const float* Wx0 = (const float*)d_in[1];
  const float* Wh0 = (const float*)d_in[2];
  const float* b0  = (const float*)d_in[3];
  const float* Wx1 = (const float*)d_in[4];
  const float* Wh1 = (const float*)d_in[5];
  const float* b1  = (const float*)d_in[6];
  const float* fcW = (const float*)d_in[7];
  const float* fcb = (const float*)d_in[8];

  char* ws = (char*)d_ws;
  u16* W1p   = (u16*)ws;                          // 16 MiB packed Wx1|Wh1
  u16* W0p   = (u16*)(ws + (16u << 20));          //  8 MiB packed Wh0
  u16* X0p   = (u16*)(ws + (24u << 20));          // 512 KiB packed Wx0
  u16* h0b   = (u16*)(ws + (25u << 20));          // 2 x 512 KiB
  u16* h1b   = (u16*)(ws + (26u << 20));          // 2 x 512 KiB
  float* h1f = (float*)(ws + (27u << 20));        // 1 MiB
  u32* bar   = (u32*)(ws + (28u << 20));          // counters

  hipMemsetAsync(ws + (25u << 20) + (1 << 19), 0, 1 << 19, stream);  // h0b[1]
  hipMemsetAsync(ws + (26u << 20) + (1 << 19), 0, 1 << 19, stream);  // h1b[1]
  hipMemsetAsync(bar, 0, 4096, stream);

  wconv<<<6272, 256, 0, stream>>>(Wx0, Wh0, Wx1, Wh1, W1p, W0p, X0p);
  lstm_persist<<<512, 256, 0, stream>>>(x, b0, b1, fcW, fcb,
                                        W1p, W0p, X0p,
                                        h0b, h1b, h1f, bar, (float*)d_out);
}